// Round 10
// baseline (1018.735 us; speedup 1.0000x reference)
//
#include <hip/hip_runtime.h>
#include <stdint.h>
#include <stddef.h>

#define AS1 __attribute__((address_space(1)))
#define AS3 __attribute__((address_space(3)))

typedef __attribute__((ext_vector_type(4))) float f32x4;
typedef __attribute__((ext_vector_type(8))) short bf16x8;

static __device__ __forceinline__ unsigned short f2b(float x) {
  union { float f; uint32_t u; } c; c.f = x;
  return (unsigned short)((c.u + 0x7FFFu + ((c.u >> 16) & 1u)) >> 16);
}
static __device__ __forceinline__ float fsig(float x) {
  return __builtin_amdgcn_rcpf(1.f + __expf(-x));
}
static __device__ __forceinline__ float ftanh(float x) {
  return 1.f - 2.f * __builtin_amdgcn_rcpf(__expf(2.f * x) + 1.f);
}

// ---------------- prep kernels ----------------

__global__ __launch_bounds__(256) void k_cvt_bf16(const float* __restrict__ s,
                                                  unsigned short* __restrict__ d,
                                                  int n4) {
  int i = blockIdx.x * 256 + threadIdx.x;
  int stride = gridDim.x * 256;
  for (; i < n4; i += stride) {
    float4 v = ((const float4*)s)[i];
    ushort4 o;
    o.x = f2b(v.x); o.y = f2b(v.y); o.z = f2b(v.z); o.w = f2b(v.w);
    ((ushort4*)d)[i] = o;
  }
}

// row-permuted f32->bf16: permuted row rp = w*64 + q*16 + j  <-  src row q*512 + w*16 + j
__global__ __launch_bounds__(128) void k_cvt_perm(const float* __restrict__ s,
                                                  unsigned short* __restrict__ d) {
  int rp = blockIdx.x;
  int w = rp >> 6, q = (rp >> 4) & 3, j = rp & 15;
  int rs = q * 512 + w * 16 + j;
  float4 v = ((const float4*)(s + (size_t)rs * 512))[threadIdx.x];
  ushort4 o;
  o.x = f2b(v.x); o.y = f2b(v.y); o.z = f2b(v.z); o.w = f2b(v.w);
  ((ushort4*)(d + (size_t)rp * 512))[threadIdx.x] = o;
}

__global__ __launch_bounds__(256) void k_bias_perm(const float* __restrict__ a,
                                                   const float* __restrict__ b,
                                                   float* __restrict__ o) {
  int rp = blockIdx.x * 256 + threadIdx.x;
  if (rp < 2048) {
    int w = rp >> 6, q = (rp >> 4) & 3, j = rp & 15;
    int rs = q * 512 + w * 16 + j;
    o[rp] = a[rs] + b[rs];
  }
}

// row m = t*16+b  <-  emb[xs[b][t]]  (bf16)
__global__ __launch_bounds__(128) void k_emb_gather(const int* __restrict__ xs,
                                                    const float* __restrict__ emb,
                                                    unsigned short* __restrict__ out) {
  int m = blockIdx.x;
  int tok = xs[(m & 15) * 128 + (m >> 4)];
  float4 v = ((const float4*)(emb + (size_t)tok * 512))[threadIdx.x];
  ushort4 o;
  o.x = f2b(v.x); o.y = f2b(v.y); o.z = f2b(v.z); o.w = f2b(v.w);
  ((ushort4*)(out + (size_t)m * 512))[threadIdx.x] = o;
}

// ---------------- bf16 GEMM, B^T layout (m97-style; used for gates) --------
__global__ __launch_bounds__(256) void k_gemm_bt(const unsigned short* __restrict__ A,
                                                 const unsigned short* __restrict__ Bt,
                                                 const float* __restrict__ bias,
                                                 float* __restrict__ C,
                                                 int M, int N, int K) {
  __shared__ unsigned short As[128 * 32];
  __shared__ unsigned short Bs[128 * 32];
  const int tiles_n = N >> 7;
  const int tm = blockIdx.x / tiles_n;
  const int tn = blockIdx.x % tiles_n;
  const int m0 = tm << 7, n0 = tn << 7;
  const int tid = threadIdx.x;
  const int wave = tid >> 6, lane = tid & 63;
  const int wr = wave >> 1, wc = wave & 1;
  f32x4 acc[4][4] = {};

  const int lo = wave * 2048 + lane * 16;
  for (int k0 = 0; k0 < K; k0 += 32) {
#pragma unroll
    for (int i = 0; i < 2; ++i) {
      int o = lo + i * 1024;
      int row = o >> 6, kb = o & 63;
      __builtin_amdgcn_global_load_lds(
          (const AS1 uint32_t*)((const char*)A + ((size_t)(m0 + row) * K + k0) * 2 + kb),
          (AS3 uint32_t*)((char*)As + wave * 2048 + i * 1024), 16, 0, 0);
    }
#pragma unroll
    for (int i = 0; i < 2; ++i) {
      int o = lo + i * 1024;
      int row = o >> 6, kb = o & 63;
      __builtin_amdgcn_global_load_lds(
          (const AS1 uint32_t*)((const char*)Bt + ((size_t)(n0 + row) * K + k0) * 2 + kb),
          (AS3 uint32_t*)((char*)Bs + wave * 2048 + i * 1024), 16, 0, 0);
    }
    __syncthreads();
    bf16x8 af[4], bfr[4];
    const int lrow = lane & 15;
    const int kb16 = (lane >> 4) * 16;
#pragma unroll
    for (int i = 0; i < 4; ++i)
      af[i] = *(const bf16x8*)((const char*)As + (wr * 64 + i * 16 + lrow) * 64 + kb16);
#pragma unroll
    for (int j = 0; j < 4; ++j)
      bfr[j] = *(const bf16x8*)((const char*)Bs + (wc * 64 + j * 16 + lrow) * 64 + kb16);
#pragma unroll
    for (int i = 0; i < 4; ++i)
#pragma unroll
      for (int j = 0; j < 4; ++j)
        acc[i][j] = __builtin_amdgcn_mfma_f32_16x16x32_bf16(af[i], bfr[j], acc[i][j], 0, 0, 0);
    __syncthreads();
  }
#pragma unroll
  for (int j = 0; j < 4; ++j) {
    int col = n0 + wc * 64 + j * 16 + (lane & 15);
    float bv = bias[col];
#pragma unroll
    for (int i = 0; i < 4; ++i) {
      int r0 = m0 + wr * 64 + i * 16 + (lane >> 4) * 4;
#pragma unroll
      for (int r = 0; r < 4; ++r)
        C[(size_t)(r0 + r) * N + col] = acc[i][j][r] + bv;
    }
  }
}

// ---------------- fused LSTM + output GEMM (strip decomposition) ----------
// 248 WGs x 256 thr, 1 WG/CU -> all co-resident by construction.
//  bid 0..7   : LSTM role (r9-proven: sentinel consumer + drain+flag producer).
//  bid 8..247 : persistent GEMM workers. Ticket unit = STRIP (m, 8 n-tiles).
//               Per strip: flag-wait(m) -> stage A-fragments ONCE into 256
//               VGPRs via agent loads (8x less agent traffic than per-tile
//               staging: 64 MB total vs 512 MB -> no coherence-point
//               contention with the LSTM exchange) -> 8 n-tiles reusing Areg,
//               streaming only B through the normal cached global_load_lds
//               path. All Areg loops fully unrolled (static indices only).

__global__ __launch_bounds__(256, 1) void k_fused(
    const float* __restrict__ gp, const unsigned short* __restrict__ wp,
    const float* __restrict__ encc, unsigned short* __restrict__ hsb,
    uint32_t* __restrict__ flags, const unsigned short* __restrict__ woutb,
    const float* __restrict__ bout, float* __restrict__ out,
    uint32_t* __restrict__ ticket) {
  __shared__ unsigned short Bs[128 * 32];
  __shared__ int sh_tile;
  __shared__ int sh_rdy;

  const int bid = blockIdx.x;
  const int tid = threadIdx.x;

  if (bid < 8) {
    // ================= LSTM role (per-wave worker, no block sync) =========
    const int w = (bid << 2) | (tid >> 6);  // worker 0..31
    const int l = tid & 63;
    const int lr = l & 15;
    const int lk = l >> 4;
    const int col = w * 16 + lr;

    bf16x8 bfr[4][16];
#pragma unroll
    for (int j = 0; j < 4; ++j)
#pragma unroll
      for (int ks = 0; ks < 16; ++ks)
        bfr[j][ks] = *(const bf16x8*)((const char*)wp +
            (size_t)(w * 64 + j * 16 + lr) * 1024 + ks * 64 + lk * 16);

    float cst[4];
#pragma unroll
    for (int r = 0; r < 4; ++r) cst[r] = encc[(lk * 4 + r) * 512 + col];

    const uint64_t K1 = 0x0001000100010001ull;
    const uint64_t K8 = 0x8000800080008000ull;
    const int u64off = lr * 128 + lk * 2;

    float gnx[4][4];
#pragma unroll
    for (int j = 0; j < 4; ++j)
#pragma unroll
      for (int r = 0; r < 4; ++r)
        gnx[j][r] = gp[(size_t)(lk * 4 + r) * 2048 + w * 64 + j * 16 + lr];

    for (int t = 0; t < 128; ++t) {
      float gcur[4][4];
#pragma unroll
      for (int j = 0; j < 4; ++j)
#pragma unroll
        for (int r = 0; r < 4; ++r) gcur[j][r] = gnx[j][r];

      union AF { uint64_t q[2]; bf16x8 v; } af[16];
      const uint64_t* hb = (const uint64_t*)(hsb + (size_t)t * 8192);
      {
        int guard = 0;
        for (;;) {
#pragma unroll
          for (int ks = 0; ks < 16; ++ks) {
            af[ks].q[0] = __hip_atomic_load(hb + u64off + ks * 8, __ATOMIC_RELAXED,
                                            __HIP_MEMORY_SCOPE_AGENT);
            af[ks].q[1] = __hip_atomic_load(hb + u64off + ks * 8 + 1, __ATOMIC_RELAXED,
                                            __HIP_MEMORY_SCOPE_AGENT);
          }
          uint64_t bad = 0;
#pragma unroll
          for (int ks = 0; ks < 16; ++ks) {
            bad |= (~af[ks].q[0] - K1) & af[ks].q[0] & K8;
            bad |= (~af[ks].q[1] - K1) & af[ks].q[1] & K8;
          }
          if (__all(bad == 0)) break;
          __builtin_amdgcn_s_sleep(1);
          if (++guard > (1 << 20)) break;  // tripwire: wrong, not hung
        }
      }

      f32x4 acc[4] = {};
#pragma unroll
      for (int ks = 0; ks < 16; ++ks) {
#pragma unroll
        for (int j = 0; j < 4; ++j)
          acc[j] = __builtin_amdgcn_mfma_f32_16x16x32_bf16(af[ks].v, bfr[j][ks],
                                                           acc[j], 0, 0, 0);
      }

      uint32_t pk[4];
#pragma unroll
      for (int r = 0; r < 4; ++r) {
        float iv = fsig(acc[0][r] + gcur[0][r]);
        float fv = fsig(acc[1][r] + gcur[1][r]);
        float gv = ftanh(acc[2][r] + gcur[2][r]);
        float ov = fsig(acc[3][r] + gcur[3][r]);
        cst[r] = fv * cst[r] + iv * gv;
        float hv = ov * ftanh(cst[r]);
        uint32_t mine = f2b(hv);
        uint32_t other = (uint32_t)__shfl_xor((int)mine, 1);
        pk[r] = mine | (other << 16);
      }
      uint32_t* hout = (uint32_t*)(hsb + (size_t)(t + 1) * 8192);
      if ((lr & 1) == 0) {
#pragma unroll
        for (int r = 0; r < 4; ++r)
          __hip_atomic_store(hout + ((lk * 4 + r) * 512 + col) / 2, pk[r],
                             __ATOMIC_RELAXED, __HIP_MEMORY_SCOPE_AGENT);
      }
      // drain h-stores, then certify the slot for GEMM consumers
      asm volatile("s_waitcnt vmcnt(0)" ::: "memory");
      if (l == 0)
        __hip_atomic_store(flags + (size_t)t * 32 + w, 1u,
                           __ATOMIC_RELAXED, __HIP_MEMORY_SCOPE_AGENT);

      if (t < 127) {
#pragma unroll
        for (int j = 0; j < 4; ++j)
#pragma unroll
          for (int r = 0; r < 4; ++r)
            gnx[j][r] = gp[(size_t)((t + 1) * 16 + lk * 4 + r) * 2048 +
                           w * 64 + j * 16 + lr];
      }
    }
  } else {
    // ================= persistent GEMM role (strips) =================
    const unsigned short* Ab = hsb + 16 * 512;  // [2048][512] bf16 (slots 1..128)
    const int wave = tid >> 6, lane = tid & 63;
    const int wr = wave >> 1, wc = wave & 1;
    const int lrow = lane & 15;
    const int ksl = lane >> 4;
    const int lo = wave * 2048 + lane * 16;

    for (;;) {
      if (tid == 0) sh_tile = (int)atomicAdd(ticket, 1u);
      __syncthreads();
      const int strip = sh_tile;
      __syncthreads();
      if (strip >= 512) break;
      const int m = strip >> 5, nblk = strip & 31;
      const int m0 = m << 7;
      const int ntiles = (250 - nblk * 8) < 8 ? (250 - nblk * 8) : 8;

      // ---- wait for rows m0..m0+127 (flags of step t = m*8+7) ----
      if (tid == 0) sh_rdy = 0;
      __syncthreads();
      {
        const uint32_t* fp = flags + (size_t)(m * 8 + 7) * 32;
        int guard = 0;
        for (;;) {
          if (tid < 64) {
            uint32_t fl = __hip_atomic_load(fp + (tid & 31), __ATOMIC_RELAXED,
                                            __HIP_MEMORY_SCOPE_AGENT);
            if (__all(fl != 0u) && tid == 0) sh_rdy = 1;
          }
          __syncthreads();
          if (sh_rdy) break;
          if (++guard > (1 << 16)) break;  // tripwire: wrong, not hung
          __builtin_amdgcn_s_sleep(8);
          __syncthreads();
        }
      }

      // ---- stage the A-strip ONCE into registers (agent scope) ----
      bf16x8 Areg[16][4];  // [ks][i] — all indices static after unroll
#pragma unroll
      for (int ks = 0; ks < 16; ++ks)
#pragma unroll
        for (int i = 0; i < 4; ++i) {
          const uint64_t* ap = (const uint64_t*)((const char*)Ab +
              ((size_t)(m0 + wr * 64 + i * 16 + lrow) * 512 + ks * 32 + ksl * 8) * 2);
          union { uint64_t q[2]; bf16x8 v; } u;
          u.q[0] = __hip_atomic_load(ap, __ATOMIC_RELAXED, __HIP_MEMORY_SCOPE_AGENT);
          u.q[1] = __hip_atomic_load(ap + 1, __ATOMIC_RELAXED, __HIP_MEMORY_SCOPE_AGENT);
          Areg[ks][i] = u.v;
        }

      // ---- n-tiles of this strip: stream B only ----
      for (int jt = 0; jt < ntiles; ++jt) {
        const int n0 = (nblk * 8 + jt) << 7;
        f32x4 acc[4][4] = {};
#pragma unroll
        for (int ks = 0; ks < 16; ++ks) {
#pragma unroll
          for (int i = 0; i < 2; ++i) {
            int o = lo + i * 1024;
            int row = o >> 6, kb = o & 63;
            __builtin_amdgcn_global_load_lds(
                (const AS1 uint32_t*)((const char*)woutb +
                    ((size_t)(n0 + row) * 512 + ks * 32) * 2 + kb),
                (AS3 uint32_t*)((char*)Bs + o), 16, 0, 0);
          }
          __syncthreads();
          bf16x8 bfr[4];
#pragma unroll
          for (int j = 0; j < 4; ++j)
            bfr[j] = *(const bf16x8*)((const char*)Bs +
                (wc * 64 + j * 16 + lrow) * 64 + ksl * 16);
#pragma unroll
          for (int i = 0; i < 4; ++i)
#pragma unroll
            for (int j = 0; j < 4; ++j)
              acc[i][j] = __builtin_amdgcn_mfma_f32_16x16x32_bf16(
                  Areg[ks][i], bfr[j], acc[i][j], 0, 0, 0);
          __syncthreads();
        }
#pragma unroll
        for (int j = 0; j < 4; ++j) {
          int colq = n0 + wc * 64 + j * 16 + (lane & 15);
          float bv = bout[colq];
#pragma unroll
          for (int i = 0; i < 4; ++i) {
            int r0 = m0 + wr * 64 + i * 16 + (lane >> 4) * 4;
#pragma unroll
            for (int r = 0; r < 4; ++r)
              out[(size_t)(r0 + r) * 32000 + colq] = acc[i][j][r] + bv;
          }
        }
      }
    }
  }
}

// ---------------- launch ----------------

extern "C" void kernel_launch(void* const* d_in, const int* in_sizes, int n_in,
                              void* d_out, int out_size, void* d_ws, size_t ws_size,
                              hipStream_t stream) {
  (void)in_sizes; (void)n_in; (void)out_size; (void)ws_size;
  const int* xs = (const int*)d_in[0];
  const float* ench = (const float*)d_in[2];
  const float* encc = (const float*)d_in[3];
  const float* emb  = (const float*)d_in[4];
  const float* Wih  = (const float*)d_in[5];
  const float* Whh  = (const float*)d_in[6];
  const float* bih  = (const float*)d_in[7];
  const float* bhh  = (const float*)d_in[8];
  const float* Wout = (const float*)d_in[9];
  const float* bout = (const float*)d_in[10];
  float* out = (float*)d_out;

  char* ws = (char*)d_ws;
  size_t off = 0;
  auto take = [&](size_t bytes) {
    char* p = ws + off;
    off += (bytes + 255) & ~(size_t)255;
    return p;
  };
  float* gates_pre      = (float*)take(2048ull * 2048 * 4);        // [T*B][4H] permuted cols
  unsigned short* hsb   = (unsigned short*)take(129ull * 16 * 512 * 2);  // h states bf16
  unsigned short* aemb  = (unsigned short*)take(2048ull * 512 * 2);
  unsigned short* wih_b = (unsigned short*)take(2048ull * 512 * 2);      // permuted rows
  unsigned short* wp_b  = (unsigned short*)take(2048ull * 512 * 2);      // permuted W_hh
  unsigned short* wout_b= (unsigned short*)take(32000ull * 512 * 2);
  float* bias1          = (float*)take(2048 * 4);                        // permuted
  uint32_t* flags       = (uint32_t*)take(128ull * 32 * 4);              // step flags
  uint32_t* ticket      = (uint32_t*)take(256);                          // strip tickets

  k_cvt_perm<<<2048, 128, 0, stream>>>(Wih, wih_b);
  k_cvt_perm<<<2048, 128, 0, stream>>>(Whh, wp_b);
  k_cvt_bf16<<<2048, 256, 0, stream>>>(Wout, wout_b, 32000 * 512 / 4);
  k_emb_gather<<<2048, 128, 0, stream>>>(xs, emb, aemb);
  k_bias_perm<<<8, 256, 0, stream>>>(bih, bhh, bias1);

  // slot 0 = enc_h (bf16); slots 1..128 = 0xFFFF sentinel
  k_cvt_bf16<<<2, 256, 0, stream>>>(ench, hsb, 16 * 512 / 4);
  hipMemsetAsync(hsb + 16 * 512, 0xFF, 128ull * 16 * 512 * 2, stream);
  hipMemsetAsync(flags, 0, 128ull * 32 * 4, stream);
  hipMemsetAsync(ticket, 0, 256, stream);

  // gates_pre = aemb @ W_ih_perm^T + (b_ih + b_hh)_perm
  k_gemm_bt<<<256, 256, 0, stream>>>(aemb, wih_b, bias1, gates_pre, 2048, 2048, 512);

  // fused LSTM (8 WGs) + strip-based flag-gated output GEMM (240 WGs)
  k_fused<<<248, 256, 0, stream>>>(gates_pre, wp_b, encc, hsb, flags,
                                   wout_b, bout, out, ticket);
}

// Round 11
// 535.858 us; speedup vs baseline: 1.9011x; 1.9011x over previous
//
#include <hip/hip_runtime.h>
#include <stdint.h>
#include <stddef.h>

#define AS1 __attribute__((address_space(1)))
#define AS3 __attribute__((address_space(3)))

typedef __attribute__((ext_vector_type(4))) float f32x4;
typedef __attribute__((ext_vector_type(8))) short bf16x8;

static __device__ __forceinline__ unsigned short f2b(float x) {
  union { float f; uint32_t u; } c; c.f = x;
  return (unsigned short)((c.u + 0x7FFFu + ((c.u >> 16) & 1u)) >> 16);
}
static __device__ __forceinline__ float fsig(float x) {
  return __builtin_amdgcn_rcpf(1.f + __expf(-x));
}
static __device__ __forceinline__ float ftanh(float x) {
  return 1.f - 2.f * __builtin_amdgcn_rcpf(__expf(2.f * x) + 1.f);
}

// ---------------- prep kernels ----------------

__global__ __launch_bounds__(256) void k_cvt_bf16(const float* __restrict__ s,
                                                  unsigned short* __restrict__ d,
                                                  int n4) {
  int i = blockIdx.x * 256 + threadIdx.x;
  int stride = gridDim.x * 256;
  for (; i < n4; i += stride) {
    float4 v = ((const float4*)s)[i];
    ushort4 o;
    o.x = f2b(v.x); o.y = f2b(v.y); o.z = f2b(v.z); o.w = f2b(v.w);
    ((ushort4*)d)[i] = o;
  }
}

// row-permuted f32->bf16: permuted row rp = w*64 + q*16 + j  <-  src row q*512 + w*16 + j
__global__ __launch_bounds__(128) void k_cvt_perm(const float* __restrict__ s,
                                                  unsigned short* __restrict__ d) {
  int rp = blockIdx.x;
  int w = rp >> 6, q = (rp >> 4) & 3, j = rp & 15;
  int rs = q * 512 + w * 16 + j;
  float4 v = ((const float4*)(s + (size_t)rs * 512))[threadIdx.x];
  ushort4 o;
  o.x = f2b(v.x); o.y = f2b(v.y); o.z = f2b(v.z); o.w = f2b(v.w);
  ((ushort4*)(d + (size_t)rp * 512))[threadIdx.x] = o;
}

__global__ __launch_bounds__(256) void k_bias_perm(const float* __restrict__ a,
                                                   const float* __restrict__ b,
                                                   float* __restrict__ o) {
  int rp = blockIdx.x * 256 + threadIdx.x;
  if (rp < 2048) {
    int w = rp >> 6, q = (rp >> 4) & 3, j = rp & 15;
    int rs = q * 512 + w * 16 + j;
    o[rp] = a[rs] + b[rs];
  }
}

// row m = t*16+b  <-  emb[xs[b][t]]  (bf16)
__global__ __launch_bounds__(128) void k_emb_gather(const int* __restrict__ xs,
                                                    const float* __restrict__ emb,
                                                    unsigned short* __restrict__ out) {
  int m = blockIdx.x;
  int tok = xs[(m & 15) * 128 + (m >> 4)];
  float4 v = ((const float4*)(emb + (size_t)tok * 512))[threadIdx.x];
  ushort4 o;
  o.x = f2b(v.x); o.y = f2b(v.y); o.z = f2b(v.z); o.w = f2b(v.w);
  ((ushort4*)(out + (size_t)m * 512))[threadIdx.x] = o;
}

// ---------------- bf16 GEMM, B^T layout (m97-style; used for gates) --------
__global__ __launch_bounds__(256) void k_gemm_bt(const unsigned short* __restrict__ A,
                                                 const unsigned short* __restrict__ Bt,
                                                 const float* __restrict__ bias,
                                                 float* __restrict__ C,
                                                 int M, int N, int K) {
  __shared__ unsigned short As[128 * 32];
  __shared__ unsigned short Bs[128 * 32];
  const int tiles_n = N >> 7;
  const int tm = blockIdx.x / tiles_n;
  const int tn = blockIdx.x % tiles_n;
  const int m0 = tm << 7, n0 = tn << 7;
  const int tid = threadIdx.x;
  const int wave = tid >> 6, lane = tid & 63;
  const int wr = wave >> 1, wc = wave & 1;
  f32x4 acc[4][4] = {};

  const int lo = wave * 2048 + lane * 16;
  for (int k0 = 0; k0 < K; k0 += 32) {
#pragma unroll
    for (int i = 0; i < 2; ++i) {
      int o = lo + i * 1024;
      int row = o >> 6, kb = o & 63;
      __builtin_amdgcn_global_load_lds(
          (const AS1 uint32_t*)((const char*)A + ((size_t)(m0 + row) * K + k0) * 2 + kb),
          (AS3 uint32_t*)((char*)As + wave * 2048 + i * 1024), 16, 0, 0);
    }
#pragma unroll
    for (int i = 0; i < 2; ++i) {
      int o = lo + i * 1024;
      int row = o >> 6, kb = o & 63;
      __builtin_amdgcn_global_load_lds(
          (const AS1 uint32_t*)((const char*)Bt + ((size_t)(n0 + row) * K + k0) * 2 + kb),
          (AS3 uint32_t*)((char*)Bs + wave * 2048 + i * 1024), 16, 0, 0);
    }
    __syncthreads();
    bf16x8 af[4], bfr[4];
    const int lrow = lane & 15;
    const int kb16 = (lane >> 4) * 16;
#pragma unroll
    for (int i = 0; i < 4; ++i)
      af[i] = *(const bf16x8*)((const char*)As + (wr * 64 + i * 16 + lrow) * 64 + kb16);
#pragma unroll
    for (int j = 0; j < 4; ++j)
      bfr[j] = *(const bf16x8*)((const char*)Bs + (wc * 64 + j * 16 + lrow) * 64 + kb16);
#pragma unroll
    for (int i = 0; i < 4; ++i)
#pragma unroll
      for (int j = 0; j < 4; ++j)
        acc[i][j] = __builtin_amdgcn_mfma_f32_16x16x32_bf16(af[i], bfr[j], acc[i][j], 0, 0, 0);
    __syncthreads();
  }
#pragma unroll
  for (int j = 0; j < 4; ++j) {
    int col = n0 + wc * 64 + j * 16 + (lane & 15);
    float bv = bias[col];
#pragma unroll
    for (int i = 0; i < 4; ++i) {
      int r0 = m0 + wr * 64 + i * 16 + (lane >> 4) * 4;
#pragma unroll
      for (int r = 0; r < 4; ++r)
        C[(size_t)(r0 + r) * N + col] = acc[i][j][r] + bv;
    }
  }
}

// ---------------- fused LSTM + aggregator + output GEMM -------------------
// 248 WGs x 256 thr; worst-case residency capacity >= 256 blocks even at
// 1 blk/CU -> all blocks resident regardless of dispatch order (deadlock-free).
//  bid 0..31  : LSTM worker w=bid on wave 0 ONLY (waves 1-3 exit) -> each
//               worker owns a CU-private VMEM queue (fixes r9/r10's 4-waves-
//               per-CU TA serialization). r8-proven sentinel consumer +
//               drain-then-flag producer.
//  bid 32     : aggregator — SOLE poller of the flag lines; publishes a
//               monotone progress counter to 8 replicated dwords. Causality:
//               data@CP -> flag@CP -> agg load -> progress store (issue-
//               dependent) -> worker load.
//  bid 33..247: GEMM workers. Poll ONLY progress[bid&7] with ~10us sleeps
//               (~500x less coherence-point pressure than r9/r10). Ticket
//               decode: strips of 8 n-tiles for m<=13, single tiles for
//               m=14,15 (kills the strip-granularity tail).

__global__ __launch_bounds__(256, 1) void k_fused(
    const float* __restrict__ gp, const unsigned short* __restrict__ wp,
    const float* __restrict__ encc, unsigned short* __restrict__ hsb,
    uint32_t* __restrict__ flags, uint32_t* __restrict__ progress,
    const unsigned short* __restrict__ woutb, const float* __restrict__ bout,
    float* __restrict__ out, uint32_t* __restrict__ ticket) {
  __shared__ unsigned short Bs[128 * 32];
  __shared__ int sh_tile;
  __shared__ int sh_rdy;

  const int bid = blockIdx.x;
  const int tid = threadIdx.x;

  if (bid < 32) {
    // ================= LSTM role: wave 0 only =================
    if (tid >= 64) return;
    const int w = bid;           // worker 0..31
    const int l = tid;
    const int lr = l & 15;
    const int lk = l >> 4;
    const int col = w * 16 + lr;

    bf16x8 bfr[4][16];
#pragma unroll
    for (int j = 0; j < 4; ++j)
#pragma unroll
      for (int ks = 0; ks < 16; ++ks)
        bfr[j][ks] = *(const bf16x8*)((const char*)wp +
            (size_t)(w * 64 + j * 16 + lr) * 1024 + ks * 64 + lk * 16);

    float cst[4];
#pragma unroll
    for (int r = 0; r < 4; ++r) cst[r] = encc[(lk * 4 + r) * 512 + col];

    const uint64_t K1 = 0x0001000100010001ull;
    const uint64_t K8 = 0x8000800080008000ull;
    const int u64off = lr * 128 + lk * 2;

    float gnx[4][4];
#pragma unroll
    for (int j = 0; j < 4; ++j)
#pragma unroll
      for (int r = 0; r < 4; ++r)
        gnx[j][r] = gp[(size_t)(lk * 4 + r) * 2048 + w * 64 + j * 16 + lr];

    for (int t = 0; t < 128; ++t) {
      float gcur[4][4];
#pragma unroll
      for (int j = 0; j < 4; ++j)
#pragma unroll
        for (int r = 0; r < 4; ++r) gcur[j][r] = gnx[j][r];

      union AF { uint64_t q[2]; bf16x8 v; } af[16];
      const uint64_t* hb = (const uint64_t*)(hsb + (size_t)t * 8192);
      {
        int guard = 0;
        for (;;) {
#pragma unroll
          for (int ks = 0; ks < 16; ++ks) {
            af[ks].q[0] = __hip_atomic_load(hb + u64off + ks * 8, __ATOMIC_RELAXED,
                                            __HIP_MEMORY_SCOPE_AGENT);
            af[ks].q[1] = __hip_atomic_load(hb + u64off + ks * 8 + 1, __ATOMIC_RELAXED,
                                            __HIP_MEMORY_SCOPE_AGENT);
          }
          uint64_t bad = 0;
#pragma unroll
          for (int ks = 0; ks < 16; ++ks) {
            bad |= (~af[ks].q[0] - K1) & af[ks].q[0] & K8;
            bad |= (~af[ks].q[1] - K1) & af[ks].q[1] & K8;
          }
          if (__all(bad == 0)) break;
          __builtin_amdgcn_s_sleep(1);
          if (++guard > (1 << 20)) break;  // tripwire: wrong, not hung
        }
      }

      f32x4 acc[4] = {};
#pragma unroll
      for (int ks = 0; ks < 16; ++ks) {
#pragma unroll
        for (int j = 0; j < 4; ++j)
          acc[j] = __builtin_amdgcn_mfma_f32_16x16x32_bf16(af[ks].v, bfr[j][ks],
                                                           acc[j], 0, 0, 0);
      }

      uint32_t pk[4];
#pragma unroll
      for (int r = 0; r < 4; ++r) {
        float iv = fsig(acc[0][r] + gcur[0][r]);
        float fv = fsig(acc[1][r] + gcur[1][r]);
        float gv = ftanh(acc[2][r] + gcur[2][r]);
        float ov = fsig(acc[3][r] + gcur[3][r]);
        cst[r] = fv * cst[r] + iv * gv;
        float hv = ov * ftanh(cst[r]);
        uint32_t mine = f2b(hv);
        uint32_t other = (uint32_t)__shfl_xor((int)mine, 1);
        pk[r] = mine | (other << 16);
      }
      uint32_t* hout = (uint32_t*)(hsb + (size_t)(t + 1) * 8192);
      if ((lr & 1) == 0) {
#pragma unroll
        for (int r = 0; r < 4; ++r)
          __hip_atomic_store(hout + ((lk * 4 + r) * 512 + col) / 2, pk[r],
                             __ATOMIC_RELAXED, __HIP_MEMORY_SCOPE_AGENT);
      }
      // drain h-stores, then certify the slot
      asm volatile("s_waitcnt vmcnt(0)" ::: "memory");
      if (l == 0)
        __hip_atomic_store(flags + (size_t)t * 32 + w, 1u,
                           __ATOMIC_RELAXED, __HIP_MEMORY_SCOPE_AGENT);

      if (t < 127) {
#pragma unroll
        for (int j = 0; j < 4; ++j)
#pragma unroll
          for (int r = 0; r < 4; ++r)
            gnx[j][r] = gp[(size_t)((t + 1) * 16 + lk * 4 + r) * 2048 +
                           w * 64 + j * 16 + lr];
      }
    }
  } else if (bid == 32) {
    // ================= aggregator: sole flag poller =================
    if (tid >= 64) return;
    const int l = tid;
    for (int t = 0; t < 128; ++t) {
      int guard = 0;
      for (;;) {
        uint32_t fl = __hip_atomic_load(flags + (size_t)t * 32 + (l & 31),
                                        __ATOMIC_RELAXED, __HIP_MEMORY_SCOPE_AGENT);
        if (__all(fl != 0u)) break;
        __builtin_amdgcn_s_sleep(4);
        if (++guard > (1 << 18)) break;  // tripwire: wrong, not hung
      }
      if (l < 8)
        __hip_atomic_store(progress + l * 64, (uint32_t)(t + 1),
                           __ATOMIC_RELAXED, __HIP_MEMORY_SCOPE_AGENT);
    }
  } else {
    // ================= persistent GEMM role =================
    const unsigned short* Ab = hsb + 16 * 512;  // [2048][512] bf16 (slots 1..128)
    const int wave = tid >> 6, lane = tid & 63;
    const int wr = wave >> 1, wc = wave & 1;
    const int lrow = lane & 15;
    const int ksl = lane >> 4;
    const int lo = wave * 2048 + lane * 16;
    const uint32_t* prog = progress + (bid & 7) * 64;

    for (;;) {
      if (tid == 0) sh_tile = (int)atomicAdd(ticket, 1u);
      __syncthreads();
      const int tk = sh_tile;
      __syncthreads();
      if (tk >= 948) break;
      int m, nb0, ntiles;
      if (tk < 448) {            // strips of 8 n-tiles, m = 0..13
        m = tk >> 5;
        int nb = tk & 31;
        nb0 = nb * 8;
        ntiles = (250 - nb0) < 8 ? (250 - nb0) : 8;
      } else {                   // single tiles for m = 14, 15
        int idx = tk - 448;
        m = 14 + idx / 250;
        nb0 = idx % 250;
        ntiles = 1;
      }
      const int m0 = m << 7;
      const uint32_t need = (uint32_t)(m * 8 + 8);

      // ---- wait on replicated progress (low-pressure, ~10us polls) ----
      if (tid == 0) sh_rdy = 0;
      __syncthreads();
      {
        int guard = 0;
        for (;;) {
          if (tid == 0) {
            uint32_t v = __hip_atomic_load(prog, __ATOMIC_RELAXED,
                                           __HIP_MEMORY_SCOPE_AGENT);
            if (v >= need) sh_rdy = 1;
          }
          __syncthreads();
          if (sh_rdy) break;
          __builtin_amdgcn_s_sleep(127);
          __builtin_amdgcn_s_sleep(127);
          __builtin_amdgcn_s_sleep(127);
          if (++guard > (1 << 14)) break;  // tripwire: wrong, not hung
          __syncthreads();
        }
      }

      // ---- stage the A-tile ONCE into registers (agent scope) ----
      bf16x8 Areg[16][4];  // [ks][i] — static indices after unroll
#pragma unroll
      for (int ks = 0; ks < 16; ++ks)
#pragma unroll
        for (int i = 0; i < 4; ++i) {
          const uint64_t* ap = (const uint64_t*)((const char*)Ab +
              ((size_t)(m0 + wr * 64 + i * 16 + lrow) * 512 + ks * 32 + ksl * 8) * 2);
          union { uint64_t q[2]; bf16x8 v; } u;
          u.q[0] = __hip_atomic_load(ap, __ATOMIC_RELAXED, __HIP_MEMORY_SCOPE_AGENT);
          u.q[1] = __hip_atomic_load(ap + 1, __ATOMIC_RELAXED, __HIP_MEMORY_SCOPE_AGENT);
          Areg[ks][i] = u.v;
        }

      // ---- n-tiles: stream B only (cached global_load_lds path) ----
      for (int jt = 0; jt < ntiles; ++jt) {
        const int n0 = (nb0 + jt) << 7;
        f32x4 acc[4][4] = {};
#pragma unroll
        for (int ks = 0; ks < 16; ++ks) {
#pragma unroll
          for (int i = 0; i < 2; ++i) {
            int o = lo + i * 1024;
            int row = o >> 6, kb = o & 63;
            __builtin_amdgcn_global_load_lds(
                (const AS1 uint32_t*)((const char*)woutb +
                    ((size_t)(n0 + row) * 512 + ks * 32) * 2 + kb),
                (AS3 uint32_t*)((char*)Bs + o), 16, 0, 0);
          }
          __syncthreads();
          bf16x8 bfr[4];
#pragma unroll
          for (int j = 0; j < 4; ++j)
            bfr[j] = *(const bf16x8*)((const char*)Bs +
                (wc * 64 + j * 16 + lrow) * 64 + ksl * 16);
#pragma unroll
          for (int i = 0; i < 4; ++i)
#pragma unroll
            for (int j = 0; j < 4; ++j)
              acc[i][j] = __builtin_amdgcn_mfma_f32_16x16x32_bf16(
                  Areg[ks][i], bfr[j], acc[i][j], 0, 0, 0);
          __syncthreads();
        }
#pragma unroll
        for (int j = 0; j < 4; ++j) {
          int colq = n0 + wc * 64 + j * 16 + (lane & 15);
          float bv = bout[colq];
#pragma unroll
          for (int i = 0; i < 4; ++i) {
            int r0 = m0 + wr * 64 + i * 16 + (lane >> 4) * 4;
#pragma unroll
            for (int r = 0; r < 4; ++r)
              out[(size_t)(r0 + r) * 32000 + colq] = acc[i][j][r] + bv;
          }
        }
      }
    }
  }
}

// ---------------- launch ----------------

extern "C" void kernel_launch(void* const* d_in, const int* in_sizes, int n_in,
                              void* d_out, int out_size, void* d_ws, size_t ws_size,
                              hipStream_t stream) {
  (void)in_sizes; (void)n_in; (void)out_size; (void)ws_size;
  const int* xs = (const int*)d_in[0];
  const float* ench = (const float*)d_in[2];
  const float* encc = (const float*)d_in[3];
  const float* emb  = (const float*)d_in[4];
  const float* Wih  = (const float*)d_in[5];
  const float* Whh  = (const float*)d_in[6];
  const float* bih  = (const float*)d_in[7];
  const float* bhh  = (const float*)d_in[8];
  const float* Wout = (const float*)d_in[9];
  const float* bout = (const float*)d_in[10];
  float* out = (float*)d_out;

  char* ws = (char*)d_ws;
  size_t off = 0;
  auto take = [&](size_t bytes) {
    char* p = ws + off;
    off += (bytes + 255) & ~(size_t)255;
    return p;
  };
  float* gates_pre      = (float*)take(2048ull * 2048 * 4);        // [T*B][4H] permuted cols
  unsigned short* hsb   = (unsigned short*)take(129ull * 16 * 512 * 2);  // h states bf16
  unsigned short* aemb  = (unsigned short*)take(2048ull * 512 * 2);
  unsigned short* wih_b = (unsigned short*)take(2048ull * 512 * 2);      // permuted rows
  unsigned short* wp_b  = (unsigned short*)take(2048ull * 512 * 2);      // permuted W_hh
  unsigned short* wout_b= (unsigned short*)take(32000ull * 512 * 2);
  float* bias1          = (float*)take(2048 * 4);                        // permuted
  uint32_t* flags       = (uint32_t*)take(128ull * 32 * 4);              // step flags
  uint32_t* progress    = (uint32_t*)take(8 * 256);                      // 8 replicas
  uint32_t* ticket      = (uint32_t*)take(256);                          // work tickets

  k_cvt_perm<<<2048, 128, 0, stream>>>(Wih, wih_b);
  k_cvt_perm<<<2048, 128, 0, stream>>>(Whh, wp_b);
  k_cvt_bf16<<<2048, 256, 0, stream>>>(Wout, wout_b, 32000 * 512 / 4);
  k_emb_gather<<<2048, 128, 0, stream>>>(xs, emb, aemb);
  k_bias_perm<<<8, 256, 0, stream>>>(bih, bhh, bias1);

  // slot 0 = enc_h (bf16); slots 1..128 = 0xFFFF sentinel
  k_cvt_bf16<<<2, 256, 0, stream>>>(ench, hsb, 16 * 512 / 4);
  hipMemsetAsync(hsb + 16 * 512, 0xFF, 128ull * 16 * 512 * 2, stream);
  hipMemsetAsync(flags, 0, 128ull * 32 * 4, stream);
  hipMemsetAsync(progress, 0, 8 * 256, stream);
  hipMemsetAsync(ticket, 0, 256, stream);

  // gates_pre = aemb @ W_ih_perm^T + (b_ih + b_hh)_perm
  k_gemm_bt<<<256, 256, 0, stream>>>(aemb, wih_b, bias1, gates_pre, 2048, 2048, 512);

  // fused: 32 LSTM (1 wave/CU) + 1 aggregator + 215 GEMM workers
  k_fused<<<248, 256, 0, stream>>>(gates_pre, wp_b, encc, hsb, flags, progress,
                                   wout_b, bout, out, ticket);
}

// Round 12
// 528.278 us; speedup vs baseline: 1.9284x; 1.0143x over previous
//
#include <hip/hip_runtime.h>
#include <stdint.h>
#include <stddef.h>

#define AS1 __attribute__((address_space(1)))
#define AS3 __attribute__((address_space(3)))

typedef __attribute__((ext_vector_type(4))) float f32x4;
typedef __attribute__((ext_vector_type(8))) short bf16x8;

static __device__ __forceinline__ unsigned short f2b(float x) {
  union { float f; uint32_t u; } c; c.f = x;
  return (unsigned short)((c.u + 0x7FFFu + ((c.u >> 16) & 1u)) >> 16);
}
static __device__ __forceinline__ float fsig(float x) {
  return __builtin_amdgcn_rcpf(1.f + __expf(-x));
}
static __device__ __forceinline__ float ftanh(float x) {
  return 1.f - 2.f * __builtin_amdgcn_rcpf(__expf(2.f * x) + 1.f);
}

#define AGLD(p) __hip_atomic_load((p), __ATOMIC_RELAXED, __HIP_MEMORY_SCOPE_AGENT)

// ---------------- prep kernels ----------------

__global__ __launch_bounds__(256) void k_cvt_bf16(const float* __restrict__ s,
                                                  unsigned short* __restrict__ d,
                                                  int n4) {
  int i = blockIdx.x * 256 + threadIdx.x;
  int stride = gridDim.x * 256;
  for (; i < n4; i += stride) {
    float4 v = ((const float4*)s)[i];
    ushort4 o;
    o.x = f2b(v.x); o.y = f2b(v.y); o.z = f2b(v.z); o.w = f2b(v.w);
    ((ushort4*)d)[i] = o;
  }
}

// row-permuted f32->bf16: permuted row rp = w*64 + q*16 + j  <-  src row q*512 + w*16 + j
__global__ __launch_bounds__(128) void k_cvt_perm(const float* __restrict__ s,
                                                  unsigned short* __restrict__ d) {
  int rp = blockIdx.x;
  int w = rp >> 6, q = (rp >> 4) & 3, j = rp & 15;
  int rs = q * 512 + w * 16 + j;
  float4 v = ((const float4*)(s + (size_t)rs * 512))[threadIdx.x];
  ushort4 o;
  o.x = f2b(v.x); o.y = f2b(v.y); o.z = f2b(v.z); o.w = f2b(v.w);
  ((ushort4*)(d + (size_t)rp * 512))[threadIdx.x] = o;
}

__global__ __launch_bounds__(256) void k_bias_perm(const float* __restrict__ a,
                                                   const float* __restrict__ b,
                                                   float* __restrict__ o) {
  int rp = blockIdx.x * 256 + threadIdx.x;
  if (rp < 2048) {
    int w = rp >> 6, q = (rp >> 4) & 3, j = rp & 15;
    int rs = q * 512 + w * 16 + j;
    o[rp] = a[rs] + b[rs];
  }
}

// row m = t*16+b  <-  emb[xs[b][t]]  (bf16)
__global__ __launch_bounds__(128) void k_emb_gather(const int* __restrict__ xs,
                                                    const float* __restrict__ emb,
                                                    unsigned short* __restrict__ out) {
  int m = blockIdx.x;
  int tok = xs[(m & 15) * 128 + (m >> 4)];
  float4 v = ((const float4*)(emb + (size_t)tok * 512))[threadIdx.x];
  ushort4 o;
  o.x = f2b(v.x); o.y = f2b(v.y); o.z = f2b(v.z); o.w = f2b(v.w);
  ((ushort4*)(out + (size_t)m * 512))[threadIdx.x] = o;
}

// ---------------- bf16 GEMM, B^T layout (m97-style; used for gates) --------
__global__ __launch_bounds__(256) void k_gemm_bt(const unsigned short* __restrict__ A,
                                                 const unsigned short* __restrict__ Bt,
                                                 const float* __restrict__ bias,
                                                 float* __restrict__ C,
                                                 int M, int N, int K) {
  __shared__ unsigned short As[128 * 32];
  __shared__ unsigned short Bs[128 * 32];
  const int tiles_n = N >> 7;
  const int tm = blockIdx.x / tiles_n;
  const int tn = blockIdx.x % tiles_n;
  const int m0 = tm << 7, n0 = tn << 7;
  const int tid = threadIdx.x;
  const int wave = tid >> 6, lane = tid & 63;
  const int wr = wave >> 1, wc = wave & 1;
  f32x4 acc[4][4] = {};

  const int lo = wave * 2048 + lane * 16;
  for (int k0 = 0; k0 < K; k0 += 32) {
#pragma unroll
    for (int i = 0; i < 2; ++i) {
      int o = lo + i * 1024;
      int row = o >> 6, kb = o & 63;
      __builtin_amdgcn_global_load_lds(
          (const AS1 uint32_t*)((const char*)A + ((size_t)(m0 + row) * K + k0) * 2 + kb),
          (AS3 uint32_t*)((char*)As + wave * 2048 + i * 1024), 16, 0, 0);
    }
#pragma unroll
    for (int i = 0; i < 2; ++i) {
      int o = lo + i * 1024;
      int row = o >> 6, kb = o & 63;
      __builtin_amdgcn_global_load_lds(
          (const AS1 uint32_t*)((const char*)Bt + ((size_t)(n0 + row) * K + k0) * 2 + kb),
          (AS3 uint32_t*)((char*)Bs + wave * 2048 + i * 1024), 16, 0, 0);
    }
    __syncthreads();
    bf16x8 af[4], bfr[4];
    const int lrow = lane & 15;
    const int kb16 = (lane >> 4) * 16;
#pragma unroll
    for (int i = 0; i < 4; ++i)
      af[i] = *(const bf16x8*)((const char*)As + (wr * 64 + i * 16 + lrow) * 64 + kb16);
#pragma unroll
    for (int j = 0; j < 4; ++j)
      bfr[j] = *(const bf16x8*)((const char*)Bs + (wc * 64 + j * 16 + lrow) * 64 + kb16);
#pragma unroll
    for (int i = 0; i < 4; ++i)
#pragma unroll
      for (int j = 0; j < 4; ++j)
        acc[i][j] = __builtin_amdgcn_mfma_f32_16x16x32_bf16(af[i], bfr[j], acc[i][j], 0, 0, 0);
    __syncthreads();
  }
#pragma unroll
  for (int j = 0; j < 4; ++j) {
    int col = n0 + wc * 64 + j * 16 + (lane & 15);
    float bv = bias[col];
#pragma unroll
    for (int i = 0; i < 4; ++i) {
      int r0 = m0 + wr * 64 + i * 16 + (lane >> 4) * 4;
#pragma unroll
      for (int r = 0; r < 4; ++r)
        C[(size_t)(r0 + r) * N + col] = acc[i][j][r] + bv;
    }
  }
}

// ---------------- fused LSTM + aggregator + output GEMM -------------------
// 248 WGs x 256 thr; residency capacity >= 256 blocks -> deadlock-free.
//  bid 0..31  : LSTM worker (wave 0 only; CU-private VMEM queue). r8-proven
//               sentinel consumer with NEW rolling half-sweep pipeline: check
//               ks0-7 (counted vmcnt), re-issue failed half while the other
//               half's loads remain in flight -> detection cadence ~RT/2.
//               Pre-gates fold into the MFMA C-init (r3-proven numerics).
//  bid 32     : aggregator — sole flag poller; publishes progress to 8
//               replicated dwords.
//  bid 33..247: GEMM workers. Strip tickets for m=0..14 (8 n-tiles), singles
//               only for m=15 (post-LSTM). A-stage staggered by (tk&7)*~.4us
//               to smear the window-open agent burst across one step period.

__global__ __launch_bounds__(256, 1) void k_fused(
    const float* __restrict__ gp, const unsigned short* __restrict__ wp,
    const float* __restrict__ encc, unsigned short* __restrict__ hsb,
    uint32_t* __restrict__ flags, uint32_t* __restrict__ progress,
    const unsigned short* __restrict__ woutb, const float* __restrict__ bout,
    float* __restrict__ out, uint32_t* __restrict__ ticket) {
  __shared__ unsigned short Bs[128 * 32];
  __shared__ int sh_tile;
  __shared__ int sh_rdy;

  const int bid = blockIdx.x;
  const int tid = threadIdx.x;

  if (bid < 32) {
    // ================= LSTM role: wave 0 only =================
    if (tid >= 64) return;
    const int w = bid;           // worker 0..31
    const int l = tid;
    const int lr = l & 15;
    const int lk = l >> 4;
    const int col = w * 16 + lr;

    bf16x8 bfr[4][16];
#pragma unroll
    for (int j = 0; j < 4; ++j)
#pragma unroll
      for (int ks = 0; ks < 16; ++ks)
        bfr[j][ks] = *(const bf16x8*)((const char*)wp +
            (size_t)(w * 64 + j * 16 + lr) * 1024 + ks * 64 + lk * 16);

    float cst[4];
#pragma unroll
    for (int r = 0; r < 4; ++r) cst[r] = encc[(lk * 4 + r) * 512 + col];

    const uint64_t K1 = 0x0001000100010001ull;
    const uint64_t K8 = 0x8000800080008000ull;
    const int u64off = lr * 128 + lk * 2;

    float gnx[4][4];
#pragma unroll
    for (int j = 0; j < 4; ++j)
#pragma unroll
      for (int r = 0; r < 4; ++r)
        gnx[j][r] = gp[(size_t)(lk * 4 + r) * 2048 + w * 64 + j * 16 + lr];

    for (int t = 0; t < 128; ++t) {
      // pre-gates as the MFMA C-init (identical math; gcur eliminated)
      f32x4 acc[4];
#pragma unroll
      for (int j = 0; j < 4; ++j)
#pragma unroll
        for (int r = 0; r < 4; ++r) acc[j][r] = gnx[j][r];

      // ---- rolling half-sweep sentinel poll ----
      union AF { uint64_t q[2]; bf16x8 v; } af[16];
      const uint64_t* hb = (const uint64_t*)(hsb + (size_t)t * 8192);
#pragma unroll
      for (int ks = 0; ks < 16; ++ks) {
        af[ks].q[0] = AGLD(hb + u64off + ks * 8);
        af[ks].q[1] = AGLD(hb + u64off + ks * 8 + 1);
      }
      bool oklo = false, okhi = false;
      int guard = 0;
      for (;;) {
        if (!oklo) {
          uint64_t bad = 0;
#pragma unroll
          for (int ks = 0; ks < 8; ++ks)
            bad |= ((~af[ks].q[0] - K1) & af[ks].q[0] & K8) |
                   ((~af[ks].q[1] - K1) & af[ks].q[1] & K8);
          oklo = __all(bad == 0);
          if (!oklo) {
#pragma unroll
            for (int ks = 0; ks < 8; ++ks) {
              af[ks].q[0] = AGLD(hb + u64off + ks * 8);
              af[ks].q[1] = AGLD(hb + u64off + ks * 8 + 1);
            }
          }
        }
        if (!okhi) {
          uint64_t bad = 0;
#pragma unroll
          for (int ks = 8; ks < 16; ++ks)
            bad |= ((~af[ks].q[0] - K1) & af[ks].q[0] & K8) |
                   ((~af[ks].q[1] - K1) & af[ks].q[1] & K8);
          okhi = __all(bad == 0);
          if (!okhi) {
#pragma unroll
            for (int ks = 8; ks < 16; ++ks) {
              af[ks].q[0] = AGLD(hb + u64off + ks * 8);
              af[ks].q[1] = AGLD(hb + u64off + ks * 8 + 1);
            }
          }
        }
        if (oklo && okhi) break;
        if (++guard > (1 << 20)) break;  // tripwire: wrong, not hung
      }

      // ---- gates = pre + h @ W^T ----
#pragma unroll
      for (int ks = 0; ks < 16; ++ks) {
#pragma unroll
        for (int j = 0; j < 4; ++j)
          acc[j] = __builtin_amdgcn_mfma_f32_16x16x32_bf16(af[ks].v, bfr[j][ks],
                                                           acc[j], 0, 0, 0);
      }

      // ---- in-lane LSTM cell; pack col pairs -> relaxed agent stores ----
      uint32_t pk[4];
#pragma unroll
      for (int r = 0; r < 4; ++r) {
        float iv = fsig(acc[0][r]);
        float fv = fsig(acc[1][r]);
        float gv = ftanh(acc[2][r]);
        float ov = fsig(acc[3][r]);
        cst[r] = fv * cst[r] + iv * gv;
        float hv = ov * ftanh(cst[r]);
        uint32_t mine = f2b(hv);
        uint32_t other = (uint32_t)__shfl_xor((int)mine, 1);
        pk[r] = mine | (other << 16);
      }
      uint32_t* hout = (uint32_t*)(hsb + (size_t)(t + 1) * 8192);
      if ((lr & 1) == 0) {
#pragma unroll
        for (int r = 0; r < 4; ++r)
          __hip_atomic_store(hout + ((lk * 4 + r) * 512 + col) / 2, pk[r],
                             __ATOMIC_RELAXED, __HIP_MEMORY_SCOPE_AGENT);
      }
      // drain h-stores, then certify the slot
      asm volatile("s_waitcnt vmcnt(0)" ::: "memory");
      if (l == 0)
        __hip_atomic_store(flags + (size_t)t * 32 + w, 1u,
                           __ATOMIC_RELAXED, __HIP_MEMORY_SCOPE_AGENT);

      if (t < 127) {
#pragma unroll
        for (int j = 0; j < 4; ++j)
#pragma unroll
          for (int r = 0; r < 4; ++r)
            gnx[j][r] = gp[(size_t)((t + 1) * 16 + lk * 4 + r) * 2048 +
                           w * 64 + j * 16 + lr];
      }
    }
  } else if (bid == 32) {
    // ================= aggregator: sole flag poller =================
    if (tid >= 64) return;
    const int l = tid;
    for (int t = 0; t < 128; ++t) {
      int guard = 0;
      for (;;) {
        uint32_t fl = AGLD(flags + (size_t)t * 32 + (l & 31));
        if (__all(fl != 0u)) break;
        __builtin_amdgcn_s_sleep(4);
        if (++guard > (1 << 18)) break;  // tripwire: wrong, not hung
      }
      if (l < 8)
        __hip_atomic_store(progress + l * 64, (uint32_t)(t + 1),
                           __ATOMIC_RELAXED, __HIP_MEMORY_SCOPE_AGENT);
    }
  } else {
    // ================= persistent GEMM role =================
    const unsigned short* Ab = hsb + 16 * 512;  // [2048][512] bf16 (slots 1..128)
    const int wave = tid >> 6, lane = tid & 63;
    const int wr = wave >> 1, wc = wave & 1;
    const int lrow = lane & 15;
    const int ksl = lane >> 4;
    const int lo = wave * 2048 + lane * 16;
    const uint32_t* prog = progress + (bid & 7) * 64;

    for (;;) {
      if (tid == 0) sh_tile = (int)atomicAdd(ticket, 1u);
      __syncthreads();
      const int tk = sh_tile;
      __syncthreads();
      if (tk >= 730) break;
      int m, nb0, ntiles;
      if (tk < 480) {            // strips of 8 n-tiles, m = 0..14
        m = tk >> 5;
        nb0 = (tk & 31) * 8;
        ntiles = (250 - nb0) < 8 ? (250 - nb0) : 8;
      } else {                   // single tiles for m = 15 (post-LSTM)
        m = 15;
        nb0 = tk - 480;
        ntiles = 1;
      }
      const int m0 = m << 7;
      const uint32_t need = (uint32_t)(m * 8 + 8);

      // ---- wait on replicated progress (low-pressure ~1.3us polls) ----
      if (tid == 0) sh_rdy = 0;
      __syncthreads();
      {
        int guard = 0;
        for (;;) {
          if (tid == 0) {
            uint32_t v = AGLD(prog);
            if (v >= need) sh_rdy = 1;
          }
          __syncthreads();
          if (sh_rdy) break;
          __builtin_amdgcn_s_sleep(48);
          if (++guard > (1 << 16)) break;  // tripwire: wrong, not hung
          __syncthreads();
        }
      }

      // ---- stagger the A-stage burst across ~one LSTM step period ----
      {
        int ph = tk & 7;
        for (int s = 0; s < ph; ++s) __builtin_amdgcn_s_sleep(16);
      }

      // ---- stage the A-tile ONCE into registers (agent scope) ----
      bf16x8 Areg[16][4];  // [ks][i] — static indices after unroll
#pragma unroll
      for (int ks = 0; ks < 16; ++ks)
#pragma unroll
        for (int i = 0; i < 4; ++i) {
          const uint64_t* ap = (const uint64_t*)((const char*)Ab +
              ((size_t)(m0 + wr * 64 + i * 16 + lrow) * 512 + ks * 32 + ksl * 8) * 2);
          union { uint64_t q[2]; bf16x8 v; } u;
          u.q[0] = AGLD(ap);
          u.q[1] = AGLD(ap + 1);
          Areg[ks][i] = u.v;
        }

      // ---- n-tiles: stream B only (cached global_load_lds path) ----
      for (int jt = 0; jt < ntiles; ++jt) {
        const int n0 = (nb0 + jt) << 7;
        f32x4 acc[4][4] = {};
#pragma unroll
        for (int ks = 0; ks < 16; ++ks) {
#pragma unroll
          for (int i = 0; i < 2; ++i) {
            int o = lo + i * 1024;
            int row = o >> 6, kb = o & 63;
            __builtin_amdgcn_global_load_lds(
                (const AS1 uint32_t*)((const char*)woutb +
                    ((size_t)(n0 + row) * 512 + ks * 32) * 2 + kb),
                (AS3 uint32_t*)((char*)Bs + o), 16, 0, 0);
          }
          __syncthreads();
          bf16x8 bfr[4];
#pragma unroll
          for (int j = 0; j < 4; ++j)
            bfr[j] = *(const bf16x8*)((const char*)Bs +
                (wc * 64 + j * 16 + lrow) * 64 + ksl * 16);
#pragma unroll
          for (int i = 0; i < 4; ++i)
#pragma unroll
            for (int j = 0; j < 4; ++j)
              acc[i][j] = __builtin_amdgcn_mfma_f32_16x16x32_bf16(
                  Areg[ks][i], bfr[j], acc[i][j], 0, 0, 0);
          __syncthreads();
        }
#pragma unroll
        for (int j = 0; j < 4; ++j) {
          int colq = n0 + wc * 64 + j * 16 + (lane & 15);
          float bv = bout[colq];
#pragma unroll
          for (int i = 0; i < 4; ++i) {
            int r0 = m0 + wr * 64 + i * 16 + (lane >> 4) * 4;
#pragma unroll
            for (int r = 0; r < 4; ++r)
              out[(size_t)(r0 + r) * 32000 + colq] = acc[i][j][r] + bv;
          }
        }
      }
    }
  }
}

// ---------------- launch ----------------

extern "C" void kernel_launch(void* const* d_in, const int* in_sizes, int n_in,
                              void* d_out, int out_size, void* d_ws, size_t ws_size,
                              hipStream_t stream) {
  (void)in_sizes; (void)n_in; (void)out_size; (void)ws_size;
  const int* xs = (const int*)d_in[0];
  const float* ench = (const float*)d_in[2];
  const float* encc = (const float*)d_in[3];
  const float* emb  = (const float*)d_in[4];
  const float* Wih  = (const float*)d_in[5];
  const float* Whh  = (const float*)d_in[6];
  const float* bih  = (const float*)d_in[7];
  const float* bhh  = (const float*)d_in[8];
  const float* Wout = (const float*)d_in[9];
  const float* bout = (const float*)d_in[10];
  float* out = (float*)d_out;

  char* ws = (char*)d_ws;
  size_t off = 0;
  auto take = [&](size_t bytes) {
    char* p = ws + off;
    off += (bytes + 255) & ~(size_t)255;
    return p;
  };
  float* gates_pre      = (float*)take(2048ull * 2048 * 4);        // [T*B][4H] permuted cols
  unsigned short* hsb   = (unsigned short*)take(129ull * 16 * 512 * 2);  // h states bf16
  unsigned short* aemb  = (unsigned short*)take(2048ull * 512 * 2);
  unsigned short* wih_b = (unsigned short*)take(2048ull * 512 * 2);      // permuted rows
  unsigned short* wp_b  = (unsigned short*)take(2048ull * 512 * 2);      // permuted W_hh
  unsigned short* wout_b= (unsigned short*)take(32000ull * 512 * 2);
  float* bias1          = (float*)take(2048 * 4);                        // permuted
  uint32_t* flags       = (uint32_t*)take(128ull * 32 * 4);              // step flags
  uint32_t* progress    = (uint32_t*)take(8 * 256);                      // 8 replicas
  uint32_t* ticket      = (uint32_t*)take(256);                          // work tickets

  k_cvt_perm<<<2048, 128, 0, stream>>>(Wih, wih_b);
  k_cvt_perm<<<2048, 128, 0, stream>>>(Whh, wp_b);
  k_cvt_bf16<<<2048, 256, 0, stream>>>(Wout, wout_b, 32000 * 512 / 4);
  k_emb_gather<<<2048, 128, 0, stream>>>(xs, emb, aemb);
  k_bias_perm<<<8, 256, 0, stream>>>(bih, bhh, bias1);

  // slot 0 = enc_h (bf16); slots 1..128 = 0xFFFF sentinel
  k_cvt_bf16<<<2, 256, 0, stream>>>(ench, hsb, 16 * 512 / 4);
  hipMemsetAsync(hsb + 16 * 512, 0xFF, 128ull * 16 * 512 * 2, stream);
  hipMemsetAsync(flags, 0, 128ull * 32 * 4, stream);
  hipMemsetAsync(progress, 0, 8 * 256, stream);
  hipMemsetAsync(ticket, 0, 256, stream);

  // gates_pre = aemb @ W_ih_perm^T + (b_ih + b_hh)_perm
  k_gemm_bt<<<256, 256, 0, stream>>>(aemb, wih_b, bias1, gates_pre, 2048, 2048, 512);

  // fused: 32 LSTM (1 wave/CU) + 1 aggregator + 215 GEMM workers
  k_fused<<<248, 256, 0, stream>>>(gates_pre, wp_b, encc, hsb, flags, progress,
                                   wout_b, bout, out, ticket);
}

// Round 13
// 421.859 us; speedup vs baseline: 2.4149x; 1.2523x over previous
//
#include <hip/hip_runtime.h>
#include <stdint.h>
#include <stddef.h>

#define AS1 __attribute__((address_space(1)))
#define AS3 __attribute__((address_space(3)))

typedef __attribute__((ext_vector_type(4))) float f32x4;
typedef __attribute__((ext_vector_type(8))) short bf16x8;

static __device__ __forceinline__ unsigned short f2b(float x) {
  union { float f; uint32_t u; } c; c.f = x;
  return (unsigned short)((c.u + 0x7FFFu + ((c.u >> 16) & 1u)) >> 16);
}
static __device__ __forceinline__ float fsig(float x) {
  return __builtin_amdgcn_rcpf(1.f + __expf(-x));
}
static __device__ __forceinline__ float ftanh(float x) {
  return 1.f - 2.f * __builtin_amdgcn_rcpf(__expf(2.f * x) + 1.f);
}

#define AGLD(p) __hip_atomic_load((p), __ATOMIC_RELAXED, __HIP_MEMORY_SCOPE_AGENT)
#define AGST(p, v) __hip_atomic_store((p), (v), __ATOMIC_RELAXED, __HIP_MEMORY_SCOPE_AGENT)

// ---------------- prep kernels ----------------

// row-permuted f32->bf16: permuted row rp = w*64 + q*16 + j  <-  src row q*512 + w*16 + j
__global__ __launch_bounds__(128) void k_cvt_perm(const float* __restrict__ s,
                                                  unsigned short* __restrict__ d) {
  int rp = blockIdx.x;
  int w = rp >> 6, q = (rp >> 4) & 3, j = rp & 15;
  int rs = q * 512 + w * 16 + j;
  float4 v = ((const float4*)(s + (size_t)rs * 512))[threadIdx.x];
  ushort4 o;
  o.x = f2b(v.x); o.y = f2b(v.y); o.z = f2b(v.z); o.w = f2b(v.w);
  ((ushort4*)(d + (size_t)rp * 512))[threadIdx.x] = o;
}

__global__ __launch_bounds__(256) void k_bias_perm(const float* __restrict__ a,
                                                   const float* __restrict__ b,
                                                   float* __restrict__ o) {
  int rp = blockIdx.x * 256 + threadIdx.x;
  if (rp < 2048) {
    int w = rp >> 6, q = (rp >> 4) & 3, j = rp & 15;
    int rs = q * 512 + w * 16 + j;
    o[rp] = a[rs] + b[rs];
  }
}

// row m = t*16+b  <-  emb[xs[b][t]]  (bf16)
__global__ __launch_bounds__(128) void k_emb_gather(const int* __restrict__ xs,
                                                    const float* __restrict__ emb,
                                                    unsigned short* __restrict__ out) {
  int m = blockIdx.x;
  int tok = xs[(m & 15) * 128 + (m >> 4)];
  float4 v = ((const float4*)(emb + (size_t)tok * 512))[threadIdx.x];
  ushort4 o;
  o.x = f2b(v.x); o.y = f2b(v.y); o.z = f2b(v.z); o.w = f2b(v.w);
  ((ushort4*)(out + (size_t)m * 512))[threadIdx.x] = o;
}

// enc_h -> hsb slot 0 in worker-major layout [w][b][collocal]
__global__ __launch_bounds__(256) void k_ench(const float* __restrict__ ench,
                                              unsigned short* __restrict__ hsb) {
  int idx = blockIdx.x * 256 + threadIdx.x;  // 0..8191
  int b = idx >> 9, c = idx & 511;
  hsb[(c >> 4) * 256 + b * 16 + (c & 15)] = f2b(ench[b * 512 + c]);
}

// ---------------- bf16 GEMM, B^T layout (m97-style; used for gates) --------
__global__ __launch_bounds__(256) void k_gemm_bt(const unsigned short* __restrict__ A,
                                                 const unsigned short* __restrict__ Bt,
                                                 const float* __restrict__ bias,
                                                 float* __restrict__ C,
                                                 int M, int N, int K) {
  __shared__ unsigned short As[128 * 32];
  __shared__ unsigned short Bs[128 * 32];
  const int tiles_n = N >> 7;
  const int tm = blockIdx.x / tiles_n;
  const int tn = blockIdx.x % tiles_n;
  const int m0 = tm << 7, n0 = tn << 7;
  const int tid = threadIdx.x;
  const int wave = tid >> 6, lane = tid & 63;
  const int wr = wave >> 1, wc = wave & 1;
  f32x4 acc[4][4] = {};

  const int lo = wave * 2048 + lane * 16;
  for (int k0 = 0; k0 < K; k0 += 32) {
#pragma unroll
    for (int i = 0; i < 2; ++i) {
      int o = lo + i * 1024;
      int row = o >> 6, kb = o & 63;
      __builtin_amdgcn_global_load_lds(
          (const AS1 uint32_t*)((const char*)A + ((size_t)(m0 + row) * K + k0) * 2 + kb),
          (AS3 uint32_t*)((char*)As + wave * 2048 + i * 1024), 16, 0, 0);
    }
#pragma unroll
    for (int i = 0; i < 2; ++i) {
      int o = lo + i * 1024;
      int row = o >> 6, kb = o & 63;
      __builtin_amdgcn_global_load_lds(
          (const AS1 uint32_t*)((const char*)Bt + ((size_t)(n0 + row) * K + k0) * 2 + kb),
          (AS3 uint32_t*)((char*)Bs + wave * 2048 + i * 1024), 16, 0, 0);
    }
    __syncthreads();
    bf16x8 af[4], bfr[4];
    const int lrow = lane & 15;
    const int kb16 = (lane >> 4) * 16;
#pragma unroll
    for (int i = 0; i < 4; ++i)
      af[i] = *(const bf16x8*)((const char*)As + (wr * 64 + i * 16 + lrow) * 64 + kb16);
#pragma unroll
    for (int j = 0; j < 4; ++j)
      bfr[j] = *(const bf16x8*)((const char*)Bs + (wc * 64 + j * 16 + lrow) * 64 + kb16);
#pragma unroll
    for (int i = 0; i < 4; ++i)
#pragma unroll
      for (int j = 0; j < 4; ++j)
        acc[i][j] = __builtin_amdgcn_mfma_f32_16x16x32_bf16(af[i], bfr[j], acc[i][j], 0, 0, 0);
    __syncthreads();
  }
#pragma unroll
  for (int j = 0; j < 4; ++j) {
    int col = n0 + wc * 64 + j * 16 + (lane & 15);
    float bv = bias[col];
#pragma unroll
    for (int i = 0; i < 4; ++i) {
      int r0 = m0 + wr * 64 + i * 16 + (lane >> 4) * 4;
#pragma unroll
      for (int r = 0; r < 4; ++r)
        C[(size_t)(r0 + r) * N + col] = acc[i][j][r] + bv;
    }
  }
}

// ---------------- fused LSTM + aggregator + output GEMM -------------------
// hsb slot layout is WORKER-MAJOR: slot s, worker w, batch b, collocal cl:
//   ushort addr = s*8192 + w*256 + b*16 + cl   (col = w*16+cl)
// Producer w writes its full 512-B block as 4 full 128-B lines per step
// (vs 16 partial lines row-major) -> fewer IF$ line ops on the visibility
// path. Consumer A-fragment (cols ks*32+lk*8..+8, batch lr) stays one 16-B
// read: byte = ks*1024 + (lk>>1)*512 + lr*32 + (lk&1)*16.
//  bid 0..31  : LSTM worker (wave 0 only), r8 sentinel consumer + flag.
//  bid 32     : aggregator -> 8 replicated progress dwords.
//  bid 33..247: GEMM workers: FIRST convert their wout slice f32->bf16
//               (agent stores; hides under the m=0 unlock window; gated by a
//               done-counter), then strip tickets m=0..14 / singles m=15.

__global__ __launch_bounds__(256, 1) void k_fused(
    const float* __restrict__ gp, const unsigned short* __restrict__ wp,
    const float* __restrict__ encc, unsigned short* __restrict__ hsb,
    uint32_t* __restrict__ flags, uint32_t* __restrict__ progress,
    const float* __restrict__ Wout, unsigned short* __restrict__ woutb,
    const float* __restrict__ bout, float* __restrict__ out,
    uint32_t* __restrict__ ticket, uint32_t* __restrict__ cvt_done) {
  __shared__ unsigned short Bs[128 * 32];
  __shared__ int sh_tile;
  __shared__ int sh_rdy;

  const int bid = blockIdx.x;
  const int tid = threadIdx.x;

  if (bid < 32) {
    // ================= LSTM role: wave 0 only =================
    if (tid >= 64) return;
    const int w = bid;           // worker 0..31
    const int l = tid;
    const int lr = l & 15;       // batch row
    const int lk = l >> 4;       // k-slice quarter
    const int col = w * 16 + lr;

    bf16x8 bfr[4][16];
#pragma unroll
    for (int j = 0; j < 4; ++j)
#pragma unroll
      for (int ks = 0; ks < 16; ++ks)
        bfr[j][ks] = *(const bf16x8*)((const char*)wp +
            (size_t)(w * 64 + j * 16 + lr) * 1024 + ks * 64 + lk * 16);

    float cst[4];
#pragma unroll
    for (int r = 0; r < 4; ++r) cst[r] = encc[(lk * 4 + r) * 512 + col];

    const uint64_t K1 = 0x0001000100010001ull;
    const uint64_t K8 = 0x8000800080008000ull;
    // worker-major consumer offset (u64 units); ks stride = 128 u64
    const int u64off = (lk >> 1) * 64 + lr * 4 + (lk & 1) * 2;

    float gnx[4][4];
#pragma unroll
    for (int j = 0; j < 4; ++j)
#pragma unroll
      for (int r = 0; r < 4; ++r)
        gnx[j][r] = gp[(size_t)(lk * 4 + r) * 2048 + w * 64 + j * 16 + lr];

    for (int t = 0; t < 128; ++t) {
      f32x4 acc[4];
#pragma unroll
      for (int j = 0; j < 4; ++j)
#pragma unroll
        for (int r = 0; r < 4; ++r) acc[j][r] = gnx[j][r];

      // ---- sentinel poll (bulk sweep) ----
      union AF { uint64_t q[2]; bf16x8 v; } af[16];
      const uint64_t* hb = (const uint64_t*)(hsb + (size_t)t * 8192);
      {
        int guard = 0;
        for (;;) {
#pragma unroll
          for (int ks = 0; ks < 16; ++ks) {
            af[ks].q[0] = AGLD(hb + u64off + ks * 128);
            af[ks].q[1] = AGLD(hb + u64off + ks * 128 + 1);
          }
          uint64_t bad = 0;
#pragma unroll
          for (int ks = 0; ks < 16; ++ks) {
            bad |= (~af[ks].q[0] - K1) & af[ks].q[0] & K8;
            bad |= (~af[ks].q[1] - K1) & af[ks].q[1] & K8;
          }
          if (__all(bad == 0)) break;
          if (++guard > (1 << 20)) break;  // tripwire: wrong, not hung
        }
      }

      // ---- gates = pre + h @ W^T ----
#pragma unroll
      for (int ks = 0; ks < 16; ++ks) {
#pragma unroll
        for (int j = 0; j < 4; ++j)
          acc[j] = __builtin_amdgcn_mfma_f32_16x16x32_bf16(af[ks].v, bfr[j][ks],
                                                           acc[j], 0, 0, 0);
      }

      // ---- in-lane LSTM cell; worker-major packed stores (full lines) ----
      uint32_t pk[4];
#pragma unroll
      for (int r = 0; r < 4; ++r) {
        float iv = fsig(acc[0][r]);
        float fv = fsig(acc[1][r]);
        float gv = ftanh(acc[2][r]);
        float ov = fsig(acc[3][r]);
        cst[r] = fv * cst[r] + iv * gv;
        float hv = ov * ftanh(cst[r]);
        uint32_t mine = f2b(hv);
        uint32_t other = (uint32_t)__shfl_xor((int)mine, 1);
        pk[r] = mine | (other << 16);
      }
      uint32_t* hout = (uint32_t*)(hsb + (size_t)(t + 1) * 8192);
      if ((lr & 1) == 0) {
        // u32 index = w*128 + (lk*4+r)*8 + lr/2  -> 512 contiguous bytes/worker
#pragma unroll
        for (int r = 0; r < 4; ++r)
          AGST(hout + w * 128 + (lk * 4 + r) * 8 + (lr >> 1), pk[r]);
      }
      // drain h-stores, then certify the slot
      asm volatile("s_waitcnt vmcnt(0)" ::: "memory");
      if (l == 0)
        AGST(flags + (size_t)t * 32 + w, 1u);

      if (t < 127) {
#pragma unroll
        for (int j = 0; j < 4; ++j)
#pragma unroll
          for (int r = 0; r < 4; ++r)
            gnx[j][r] = gp[(size_t)((t + 1) * 16 + lk * 4 + r) * 2048 +
                           w * 64 + j * 16 + lr];
      }
    }
  } else if (bid == 32) {
    // ================= aggregator: sole flag poller =================
    if (tid >= 64) return;
    const int l = tid;
    for (int t = 0; t < 128; ++t) {
      int guard = 0;
      for (;;) {
        uint32_t fl = AGLD(flags + (size_t)t * 32 + (l & 31));
        if (__all(fl != 0u)) break;
        __builtin_amdgcn_s_sleep(4);
        if (++guard > (1 << 18)) break;  // tripwire: wrong, not hung
      }
      if (l < 8)
        AGST(progress + l * 64, (uint32_t)(t + 1));
    }
  } else {
    // ================= persistent GEMM role =================
    // ---- phase 0: convert my wout slice f32 -> bf16 (agent stores) ----
    {
      const int gid = bid - 33;                 // 0..214
      const int CH = 19052;                     // float4 chunks per worker
      int start = gid * CH;
      int end = start + CH; if (end > 4096000) end = 4096000;
      for (int idx = start + tid; idx < end; idx += 256) {
        float4 v = ((const float4*)Wout)[idx];
        uint32_t lo = (uint32_t)f2b(v.x) | ((uint32_t)f2b(v.y) << 16);
        uint32_t hi = (uint32_t)f2b(v.z) | ((uint32_t)f2b(v.w) << 16);
        AGST((uint64_t*)woutb + idx, (uint64_t)lo | ((uint64_t)hi << 32));
      }
      asm volatile("s_waitcnt vmcnt(0)" ::: "memory");
      __syncthreads();
      if (tid == 0) {
        atomicAdd(cvt_done, 1u);
        sh_rdy = 0;
      }
      __syncthreads();
      int guard = 0;
      for (;;) {
        if (tid == 0 && AGLD(cvt_done) >= 215u) sh_rdy = 1;
        __syncthreads();
        if (sh_rdy) break;
        __builtin_amdgcn_s_sleep(16);
        if (++guard > (1 << 18)) break;  // tripwire: wrong, not hung
        __syncthreads();
      }
    }

    const int wave = tid >> 6, lane = tid & 63;
    const int wr = wave >> 1, wc = wave & 1;
    const int lrow = lane & 15;
    const int ksl = lane >> 4;
    const int lo = wave * 2048 + lane * 16;
    const uint32_t* prog = progress + (bid & 7) * 64;
    const uint64_t* Ab64 = (const uint64_t*)(hsb + 8192);  // slots 1..128

    for (;;) {
      if (tid == 0) sh_tile = (int)atomicAdd(ticket, 1u);
      __syncthreads();
      const int tk = sh_tile;
      __syncthreads();
      if (tk >= 730) break;
      int m, nb0, ntiles;
      if (tk < 480) {            // strips of 8 n-tiles, m = 0..14
        m = tk >> 5;
        nb0 = (tk & 31) * 8;
        ntiles = (250 - nb0) < 8 ? (250 - nb0) : 8;
      } else {                   // single tiles for m = 15 (post-LSTM)
        m = 15;
        nb0 = tk - 480;
        ntiles = 1;
      }
      const int m0 = m << 7;
      const uint32_t need = (uint32_t)(m * 8 + 8);

      // ---- wait on replicated progress ----
      if (tid == 0) sh_rdy = 0;
      __syncthreads();
      {
        int guard = 0;
        for (;;) {
          if (tid == 0) {
            uint32_t v = AGLD(prog);
            if (v >= need) sh_rdy = 1;
          }
          __syncthreads();
          if (sh_rdy) break;
          __builtin_amdgcn_s_sleep(48);
          if (++guard > (1 << 16)) break;  // tripwire: wrong, not hung
          __syncthreads();
        }
      }

      // ---- stagger the A-stage burst ----
      {
        int ph = tk & 7;
        for (int s = 0; s < ph; ++s) __builtin_amdgcn_s_sleep(16);
      }

      // ---- stage the A-tile into registers (agent loads, worker-major) ----
      bf16x8 Areg[16][4];  // [ks][i] — static indices after unroll
#pragma unroll
      for (int ks = 0; ks < 16; ++ks)
#pragma unroll
        for (int i = 0; i < 4; ++i) {
          // slot-major u64 index: (m*8+wr*4+i)*2048 + (2ks+(ksl>>1))*64
          //                       + lrow*4 + (ksl&1)*2
          const uint64_t* ap = Ab64 + (size_t)(m * 8 + wr * 4 + i) * 2048 +
              (2 * ks + (ksl >> 1)) * 64 + lrow * 4 + (ksl & 1) * 2;
          union { uint64_t q[2]; bf16x8 v; } u;
          u.q[0] = AGLD(ap);
          u.q[1] = AGLD(ap + 1);
          Areg[ks][i] = u.v;
        }

      // ---- n-tiles: stream B only (cached global_load_lds path) ----
      for (int jt = 0; jt < ntiles; ++jt) {
        const int n0 = (nb0 + jt) << 7;
        f32x4 acc[4][4] = {};
#pragma unroll
        for (int ks = 0; ks < 16; ++ks) {
#pragma unroll
          for (int i = 0; i < 2; ++i) {
            int o = lo + i * 1024;
            int row = o >> 6, kb = o & 63;
            __builtin_amdgcn_global_load_lds(
                (const AS1 uint32_t*)((const char*)woutb +
                    ((size_t)(n0 + row) * 512 + ks * 32) * 2 + kb),
                (AS3 uint32_t*)((char*)Bs + o), 16, 0, 0);
          }
          __syncthreads();
          bf16x8 bfr[4];
#pragma unroll
          for (int j = 0; j < 4; ++j)
            bfr[j] = *(const bf16x8*)((const char*)Bs +
                (wc * 64 + j * 16 + lrow) * 64 + ksl * 16);
#pragma unroll
          for (int i = 0; i < 4; ++i)
#pragma unroll
            for (int j = 0; j < 4; ++j)
              acc[i][j] = __builtin_amdgcn_mfma_f32_16x16x32_bf16(
                  Areg[ks][i], bfr[j], acc[i][j], 0, 0, 0);
          __syncthreads();
        }
#pragma unroll
        for (int j = 0; j < 4; ++j) {
          int colq = n0 + wc * 64 + j * 16 + (lane & 15);
          float bv = bout[colq];
#pragma unroll
          for (int i = 0; i < 4; ++i) {
            int r0 = m0 + wr * 64 + i * 16 + (lane >> 4) * 4;
#pragma unroll
            for (int r = 0; r < 4; ++r)
              out[(size_t)(r0 + r) * 32000 + colq] = acc[i][j][r] + bv;
          }
        }
      }
    }
  }
}

// ---------------- launch ----------------

extern "C" void kernel_launch(void* const* d_in, const int* in_sizes, int n_in,
                              void* d_out, int out_size, void* d_ws, size_t ws_size,
                              hipStream_t stream) {
  (void)in_sizes; (void)n_in; (void)out_size; (void)ws_size;
  const int* xs = (const int*)d_in[0];
  const float* ench = (const float*)d_in[2];
  const float* encc = (const float*)d_in[3];
  const float* emb  = (const float*)d_in[4];
  const float* Wih  = (const float*)d_in[5];
  const float* Whh  = (const float*)d_in[6];
  const float* bih  = (const float*)d_in[7];
  const float* bhh  = (const float*)d_in[8];
  const float* Wout = (const float*)d_in[9];
  const float* bout = (const float*)d_in[10];
  float* out = (float*)d_out;

  char* ws = (char*)d_ws;
  size_t off = 0;
  auto take = [&](size_t bytes) {
    char* p = ws + off;
    off += (bytes + 255) & ~(size_t)255;
    return p;
  };
  float* gates_pre      = (float*)take(2048ull * 2048 * 4);        // [T*B][4H] permuted cols
  unsigned short* hsb   = (unsigned short*)take(129ull * 16 * 512 * 2);  // worker-major slots
  unsigned short* aemb  = (unsigned short*)take(2048ull * 512 * 2);
  unsigned short* wih_b = (unsigned short*)take(2048ull * 512 * 2);      // permuted rows
  unsigned short* wp_b  = (unsigned short*)take(2048ull * 512 * 2);      // permuted W_hh
  unsigned short* wout_b= (unsigned short*)take(32000ull * 512 * 2);
  float* bias1          = (float*)take(2048 * 4);                        // permuted
  uint32_t* flags       = (uint32_t*)take(128ull * 32 * 4);              // step flags
  uint32_t* progress    = (uint32_t*)take(8 * 256);                      // 8 replicas
  uint32_t* ticket      = (uint32_t*)take(256);                          // work tickets
  uint32_t* cvt_done    = (uint32_t*)take(256);                          // convert gate

  k_cvt_perm<<<2048, 128, 0, stream>>>(Wih, wih_b);
  k_cvt_perm<<<2048, 128, 0, stream>>>(Whh, wp_b);
  k_emb_gather<<<2048, 128, 0, stream>>>(xs, emb, aemb);
  k_bias_perm<<<8, 256, 0, stream>>>(bih, bhh, bias1);

  // slot 0 = enc_h (worker-major); slots 1..128 = 0xFFFF sentinel
  k_ench<<<32, 256, 0, stream>>>(ench, hsb);
  hipMemsetAsync(hsb + 16 * 512, 0xFF, 128ull * 16 * 512 * 2, stream);
  hipMemsetAsync(flags, 0, 128ull * 32 * 4, stream);
  hipMemsetAsync(progress, 0, 8 * 256, stream);
  hipMemsetAsync(ticket, 0, 256, stream);
  hipMemsetAsync(cvt_done, 0, 256, stream);

  // gates_pre = aemb @ W_ih_perm^T + (b_ih + b_hh)_perm
  k_gemm_bt<<<256, 256, 0, stream>>>(aemb, wih_b, bias1, gates_pre, 2048, 2048, 512);

  // fused: 32 LSTM (1 wave/CU) + 1 aggregator + 215 GEMM workers
  // (wout f32->bf16 conversion happens inside, under the m=0 unlock window)
  k_fused<<<248, 256, 0, stream>>>(gates_pre, wp_b, encc, hsb, flags, progress,
                                   Wout, wout_b, bout, out, ticket, cvt_done);
}